// Round 1
// baseline (3056.317 us; speedup 1.0000x reference)
//
#include <hip/hip_runtime.h>
#include <math.h>

#define S_LEN 1024
#define B_DIM 128
#define D_DIM 64
#define H_DIM 128
#define O_DIM 512
#define K_DIM 896            // 7*H
#define M_DIM 131072         // B*S

// -------- kernel 1: encoder  pt[t*B*H + b*H + h] = x[b,t,:]·We[h,:] + be[h]
__global__ __launch_bounds__(256) void enc_kernel(
    const float* __restrict__ x, const float* __restrict__ We,
    const float* __restrict__ be, float* __restrict__ pt) {
  __shared__ __align__(16) float xs[128];
  int tid = threadIdx.x;
  long q0 = (long)blockIdx.x * 2;          // two (b,t) pairs per block
  if (tid < 128) xs[tid] = x[q0 * 64 + tid];
  __syncthreads();
  int half = tid >> 7;                     // 0/1 -> which pair
  int h = tid & 127;
  long q = q0 + half;                      // q = b*S + t
  const float4* w4 = (const float4*)(We + (long)h * 64);
  const float4* x4 = (const float4*)(xs + half * 64);
  float acc = 0.f;
#pragma unroll
  for (int i = 0; i < 16; ++i) {
    float4 a = x4[i];
    float4 b = w4[i];
    acc += a.x * b.x + a.y * b.y + a.z * b.z + a.w * b.w;
  }
  acc += be[h];
  int b = (int)(q >> 10);
  int t = (int)(q & 1023);
  pt[(long)t * 16384 + b * 128 + h] = acc;
}

// -------- kernel 2: is_rep[t] = all(x[:,t,:] == x[:,t-1,:]); rep[0]=0
__global__ __launch_bounds__(256) void rep_kernel(const float* __restrict__ x,
                                                  int* __restrict__ rep) {
  int t = blockIdx.x;
  int tid = threadIdx.x;
  if (t == 0) {
    if (tid == 0) rep[0] = 0;
    return;
  }
  int ok = 1;
  for (int j = tid; j < B_DIM * D_DIM; j += 256) {
    int b = j >> 6, d = j & 63;
    long i1 = (long)b * S_LEN * 64 + (long)t * 64 + d;
    if (x[i1] != x[i1 - 64]) ok = 0;
  }
  ok = __syncthreads_and(ok);
  if (tid == 0) rep[t] = ok;
}

// -------- kernel 3: sequential scan over t, one thread per (b,h)
__global__ __launch_bounds__(64) void scan_kernel(
    const float* __restrict__ pt, const float* __restrict__ omega,
    const int* __restrict__ rep, float* __restrict__ ph_out,
    float* __restrict__ wb_out) {
  __shared__ int reps[1024];
  int tid = threadIdx.x;
  for (int i = tid; i < 1024; i += 64) reps[i] = rep[i];
  __syncthreads();
  int g = blockIdx.x * 64 + tid;           // 0..16383
  int b = g >> 7, h = g & 127;
  float om = omega[h];
  float ph = 0.f, wb = 0.f;
  long obase = (long)b * (S_LEN * 128) + h;
  float cur[16], nxt[16];
#pragma unroll
  for (int u = 0; u < 16; ++u) cur[u] = pt[(long)u * 16384 + g];
  for (int t0 = 0; t0 < S_LEN; t0 += 16) {
    // prefetch next chunk (clamped: last chunk re-reads valid data, unused)
#pragma unroll
    for (int u = 0; u < 16; ++u) {
      int tl = t0 + 16 + u;
      if (tl > 1023) tl = 1023;
      nxt[u] = pt[(long)tl * 16384 + g];
    }
#pragma unroll
    for (int u = 0; u < 16; ++u) {
      int t = t0 + u;
      float th = cur[u];
      wb += 0.015625f;                                   // wb += WOBBLE_STEP
      // ph_new = ph + omega - sin(theta-ph) + 0.25*sin(wb); sin(theta-x)==sin(pt-x)
      ph = ph + om - sinf(th - ph) + 0.25f * sinf(wb);
      if (reps[t]) wb = wb + 0.25f * sinf(th - wb);      // only on repeats
      ph_out[obase + (long)t * 128] = ph;
      wb_out[obase + (long)t * 128] = wb;
    }
#pragma unroll
    for (int u = 0; u < 16; ++u) cur[u] = nxt[u];
  }
}

// -------- kernel 4: logits = feats @ Wr.T + br, feats recomputed from ph/wb
// BM=64 rows, BN=128 cols, 256 threads, TM=4, TN=8, K-chunks of 8 h (56 k).
__global__ __launch_bounds__(256) void out_gemm(
    const float* __restrict__ ph_hist, const float* __restrict__ wb_hist,
    const float* __restrict__ Wr, const float* __restrict__ br,
    float* __restrict__ out) {
  __shared__ __align__(16) float fa[56 * 68];    // [k=f*8+hh][row], pad 68
  __shared__ __align__(16) float fb[56 * 136];   // [k][o], pad 136
  int tid = threadIdx.x;
  int tx = tid & 15;                       // o group: cols tx*8 .. +8
  int ty = tid >> 4;                       // row group: rows ty*4 .. +4
  long rBlock = (long)blockIdx.x * 64;
  int oBlock = blockIdx.y * 128;
  float acc[4][8];
#pragma unroll
  for (int i = 0; i < 4; ++i)
#pragma unroll
    for (int j = 0; j < 8; ++j) acc[i][j] = 0.f;

  int hhA = tid & 7;                       // staging position
  int rowA = tid >> 3;                     // 0..31

  for (int c = 0; c < 16; ++c) {
    int h0 = c * 8;
    __syncthreads();
    // ---- stage feats tile (64 rows x 56 k) from ph/wb hist
#pragma unroll
    for (int pp = 0; pp < 2; ++pp) {
      int row = rowA + pp * 32;
      long r = rBlock + row;
      float ph = ph_hist[r * 128 + h0 + hhA];
      float wb = wb_hist[r * 128 + h0 + hhA];
      float phs = 0.5f * ph;
      fa[(0 * 8 + hhA) * 68 + row] = cosf(ph);
      fa[(1 * 8 + hhA) * 68 + row] = sinf(ph);
      fa[(2 * 8 + hhA) * 68 + row] = cosf(phs);
      fa[(3 * 8 + hhA) * 68 + row] = sinf(phs);
      fa[(4 * 8 + hhA) * 68 + row] = cosf(wb);
      fa[(5 * 8 + hhA) * 68 + row] = sinf(wb);
      fa[(6 * 8 + hhA) * 68 + row] = ph;
    }
    // ---- stage Wr tile (128 o x 56 k): Wr[o, f*128 + h0 + hh]
#pragma unroll
    for (int i = 0; i < 28; ++i) {
      int j = tid + 256 * i;               // 0..7167
      int hh = j & 7;
      int f = (j >> 3) % 7;
      int o = j / 56;
      fb[(f * 8 + hh) * 136 + o] =
          Wr[(long)(oBlock + o) * 896 + f * 128 + h0 + hh];
    }
    __syncthreads();
    // ---- inner product
#pragma unroll 8
    for (int kk = 0; kk < 56; ++kk) {
      float4 av = *(const float4*)&fa[kk * 68 + ty * 4];
      float4 b0 = *(const float4*)&fb[kk * 136 + tx * 8];
      float4 b1 = *(const float4*)&fb[kk * 136 + tx * 8 + 4];
      float a[4] = {av.x, av.y, av.z, av.w};
      float bb[8] = {b0.x, b0.y, b0.z, b0.w, b1.x, b1.y, b1.z, b1.w};
#pragma unroll
      for (int i = 0; i < 4; ++i)
#pragma unroll
        for (int j = 0; j < 8; ++j) acc[i][j] += a[i] * bb[j];
    }
  }
  // ---- epilogue: add bias, store
  float4 br0 = *(const float4*)&br[oBlock + tx * 8];
  float4 br1 = *(const float4*)&br[oBlock + tx * 8 + 4];
#pragma unroll
  for (int i = 0; i < 4; ++i) {
    long r = rBlock + ty * 4 + i;
    float4 v0, v1;
    v0.x = acc[i][0] + br0.x;
    v0.y = acc[i][1] + br0.y;
    v0.z = acc[i][2] + br0.z;
    v0.w = acc[i][3] + br0.w;
    v1.x = acc[i][4] + br1.x;
    v1.y = acc[i][5] + br1.y;
    v1.z = acc[i][6] + br1.z;
    v1.w = acc[i][7] + br1.w;
    *(float4*)&out[r * 512 + oBlock + tx * 8] = v0;
    *(float4*)&out[r * 512 + oBlock + tx * 8 + 4] = v1;
  }
}

extern "C" void kernel_launch(void* const* d_in, const int* in_sizes, int n_in,
                              void* d_out, int out_size, void* d_ws,
                              size_t ws_size, hipStream_t stream) {
  (void)in_sizes; (void)n_in; (void)d_ws; (void)ws_size; (void)out_size;
  const float* x = (const float*)d_in[0];
  const float* We = (const float*)d_in[1];
  const float* be = (const float*)d_in[2];
  const float* omega = (const float*)d_in[3];
  const float* Wr = (const float*)d_in[4];
  const float* br = (const float*)d_in[5];

  float* out = (float*)d_out;
  float* logits = out;                               // [B,S,O] = [M,512]
  float* ph_hist = out + (long)M_DIM * O_DIM;        // [B,S,H] = [M,128]
  float* wb_hist = ph_hist + (long)M_DIM * H_DIM;    // [B,S,H]

  // scratch inside the (later overwritten) logits region:
  float* pt = logits;                                // [S,B,H] 16.8M floats
  int* rep = (int*)(logits + 40l * 1024 * 1024);     // 1024 ints, past pt

  enc_kernel<<<M_DIM / 2, 256, 0, stream>>>(x, We, be, pt);
  rep_kernel<<<S_LEN, 256, 0, stream>>>(x, rep);
  scan_kernel<<<256, 64, 0, stream>>>(pt, omega, rep, ph_hist, wb_hist);
  dim3 g(M_DIM / 64, O_DIM / 128);
  out_gemm<<<g, 256, 0, stream>>>(ph_hist, wb_hist, Wr, br, logits);
}